// Round 2
// baseline (959.295 us; speedup 1.0000x reference)
//
#include <hip/hip_runtime.h>
#include <stdint.h>

#define BB   16
#define NN   300000
#define PRE  1000
#define NBINS 16384          // 14-bit key histogram
#define KSHIFT 18            // 32-14
#define CAP  2048

// ---------------- workspace layout (bytes) ----------------
constexpr size_t SZ_HIST   = (size_t)BB * NBINS * 4;            // 1 MiB
constexpr size_t OFF_CNT   = SZ_HIST;                           // B u32 (candidate counters)
constexpr size_t OFF_T     = OFF_CNT + 256;                     // B u32 (threshold bin)
constexpr size_t OFF_SCALE = OFF_T + 256;                       // B f32 (max+1)
constexpr size_t OFF_CAND  = OFF_SCALE + 256;                   // B*CAP u64
constexpr size_t OFF_SCORE = OFF_CAND + (size_t)BB * CAP * 8;   // B*PRE f32
constexpr size_t OFF_BC    = OFF_SCORE + (size_t)BB * PRE * 4;  // B*PRE float4 (clipped boxes)
constexpr size_t OFF_LVL   = OFF_BC + (size_t)BB * PRE * 16;    // B*PRE i32
constexpr size_t OFF_VALID = OFF_LVL + (size_t)BB * PRE * 4;    // B*16 u64
constexpr size_t OFF_KEEP  = OFF_VALID + (size_t)BB * 16 * 8;   // B*16 u64
constexpr size_t OFF_MASK  = OFF_KEEP + (size_t)BB * 16 * 8;    // B*16*PRE u64 (2 MB), layout [b][word][i]
constexpr size_t MEMSET_BYTES = OFF_CAND;                       // hist + counters need zeroing

// float -> order-preserving u32 key (ascending)
__device__ __forceinline__ unsigned f2key(float f) {
  unsigned u = __float_as_uint(f);
  return (u & 0x80000000u) ? ~u : (u | 0x80000000u);
}

// ---------------- K1: per-batch 14-bit histogram ----------------
__global__ __launch_bounds__(256) void k_hist(const float4* __restrict__ obj4,
                                              unsigned* __restrict__ hist) {
  unsigned g = blockIdx.x * 256u + threadIdx.x;
  if (g >= (BB * NN / 4)) return;
  unsigned b = g / (NN / 4);
  float4 v = obj4[g];
  unsigned* h = hist + (size_t)b * NBINS;
  atomicAdd(&h[f2key(v.x) >> KSHIFT], 1u);
  atomicAdd(&h[f2key(v.y) >> KSHIFT], 1u);
  atomicAdd(&h[f2key(v.z) >> KSHIFT], 1u);
  atomicAdd(&h[f2key(v.w) >> KSHIFT], 1u);
}

// ---------------- K2: find per-batch threshold bin ----------------
__global__ __launch_bounds__(256) void k_thresh(const unsigned* __restrict__ hist,
                                                unsigned* __restrict__ Tarr) {
  __shared__ unsigned part[256];
  int b = blockIdx.x, t = threadIdx.x;
  const uint4* h4 = (const uint4*)(hist + (size_t)b * NBINS);
  unsigned s = 0;
  for (int j = 0; j < 16; j++) { uint4 v = h4[t * 16 + j]; s += v.x + v.y + v.z + v.w; }
  part[t] = s;   // sum of bins [t*64, t*64+64)
  __syncthreads();
  if (t == 0) {
    unsigned run = 0; int c = 255;
    for (; c > 0; c--) { if (run + part[c] >= (unsigned)PRE) break; run += part[c]; }
    // scan chunk c's 64 bins from the top
    const unsigned* hb = hist + (size_t)b * NBINS + c * 64;
    unsigned T = 0;
    for (int j = 63; j >= 0; j--) {
      run += hb[j];
      if (run >= (unsigned)PRE) { T = (unsigned)(c * 64 + j); break; }
    }
    Tarr[b] = T;
  }
}

// ---------------- K3: collect candidates >= threshold ----------------
__global__ __launch_bounds__(256) void k_collect(const float4* __restrict__ obj4,
                                                 const unsigned* __restrict__ Tarr,
                                                 unsigned* __restrict__ cnt,
                                                 uint64_t* __restrict__ cand) {
  unsigned g = blockIdx.x * 256u + threadIdx.x;
  if (g >= (BB * NN / 4)) return;
  unsigned b = g / (NN / 4);
  unsigned n0 = (g - b * (NN / 4)) * 4u;
  float4 v = obj4[g];
  unsigned T = Tarr[b];
  float fs[4] = {v.x, v.y, v.z, v.w};
#pragma unroll
  for (int q = 0; q < 4; q++) {
    unsigned key = f2key(fs[q]);
    if ((key >> KSHIFT) >= T) {
      unsigned pos = atomicAdd(&cnt[b], 1u);
      if (pos < CAP)
        cand[(size_t)b * CAP + pos] = ((uint64_t)key << 32) | (unsigned)~(n0 + q);
    }
  }
}

// ---------------- K4: per-batch bitonic sort + clip/valid/scale prep ----------------
__global__ __launch_bounds__(1024) void k_sortprep(
    const uint64_t* __restrict__ cand, const unsigned* __restrict__ cnt,
    const float4* __restrict__ prop, const int* __restrict__ lvls,
    const int* __restrict__ ph, const int* __restrict__ pw,
    float* __restrict__ score, float4* __restrict__ bc, int* __restrict__ lvlT,
    uint64_t* __restrict__ validW, float* __restrict__ scale) {
  __shared__ uint64_t arr[CAP];
  __shared__ float red[16];
  int b = blockIdx.x, t = threadIdx.x;
  unsigned m = cnt[b]; if (m > CAP) m = CAP;
  for (int i = t; i < CAP; i += 1024) arr[i] = (i < (int)m) ? cand[(size_t)b * CAP + i] : 0ull;
  __syncthreads();
  for (unsigned k = 2; k <= CAP; k <<= 1) {
    for (unsigned j = k >> 1; j > 0; j >>= 1) {
      for (unsigned i = t; i < CAP; i += 1024) {
        unsigned ixj = i ^ j;
        if (ixj > i) {
          uint64_t a = arr[i], c2 = arr[ixj];
          bool sw = ((i & k) == 0) ? (a > c2) : (a < c2);
          if (sw) { arr[i] = c2; arr[ixj] = a; }
        }
      }
      __syncthreads();
    }
  }
  float W = (float)(*pw), H = (float)(*ph);
  float lm = 0.0f; bool valid = false;
  if (t < PRE) {
    uint64_t c = arr[CAP - 1 - t];          // rank t (descending, ties by lower idx)
    unsigned key = (unsigned)(c >> 32);
    unsigned idx = ~((unsigned)c);
    if (idx >= NN) idx = 0;                 // crash-proof clamp (never hit in valid data)
    unsigned ub = (key & 0x80000000u) ? (key & 0x7FFFFFFFu) : ~key;
    float4 p = prop[(size_t)b * NN + idx];
    float x1 = fminf(fmaxf(p.x, 0.0f), W);
    float y1 = fminf(fmaxf(p.y, 0.0f), H);
    float x2 = fminf(fmaxf(p.z, 0.0f), W);
    float y2 = fminf(fmaxf(p.w, 0.0f), H);
    valid = ((x2 - x1) > 0.001f) && ((y2 - y1) > 0.001f);
    bc[(size_t)b * PRE + t] = make_float4(x1, y1, x2, y2);
    score[b * PRE + t] = __uint_as_float(ub);
    lvlT[b * PRE + t] = lvls[idx];
    lm = fmaxf(fmaxf(x1, y1), fmaxf(x2, y2));
  }
  uint64_t bal = __ballot(valid);
  if ((t & 63) == 0) validW[b * 16 + (t >> 6)] = bal;
  for (int o = 32; o > 0; o >>= 1) lm = fmaxf(lm, __shfl_xor(lm, o, 64));
  if ((t & 63) == 0) red[t >> 6] = lm;
  __syncthreads();
  if (t == 0) {
    float mm = red[0];
    for (int i = 1; i < 16; i++) mm = fmaxf(mm, red[i]);
    scale[b] = mm + 1.0f;                   // jnp.max(bc) + 1.0
  }
}

// ---------------- K5: suppression bitmask (iou(i,j)>0.7 & j>i) ----------------
__global__ __launch_bounds__(256) void k_mask(const float4* __restrict__ bc,
                                              const int* __restrict__ lvlT,
                                              const float* __restrict__ scale,
                                              uint64_t* __restrict__ mask) {
  __shared__ float sx1[PRE], sy1[PRE], sx2[PRE], sy2[PRE], sar[PRE];
  int tile = blockIdx.x, b = blockIdx.y, t = threadIdx.x;
  float sc = scale[b];
  for (int i = t; i < PRE; i += 256) {
    float4 v = bc[(size_t)b * PRE + i];
    float off = (float)lvlT[b * PRE + i] * sc;
    float x1 = v.x + off, y1 = v.y + off, x2 = v.z + off, y2 = v.w + off;
    sx1[i] = x1; sy1[i] = y1; sx2[i] = x2; sy2[i] = y2;
    sar[i] = fmaxf(x2 - x1, 0.0f) * fmaxf(y2 - y1, 0.0f);   // area on OFFSET coords (matches ref)
  }
  __syncthreads();
#pragma unroll
  for (int pass = 0; pass < 4; pass++) {
    int tau = t + 256 * pass;
    int w = tau >> 6;                 // wave-uniform word -> LDS broadcast on j reads
    int i = tile * 64 + (tau & 63);   // lane-varying row  -> stride-1 LDS on i reads
    if (i < PRE) {
      float bx1 = sx1[i], by1 = sy1[i], bx2 = sx2[i], by2 = sy2[i], ba = sar[i];
      uint64_t mm = 0;
      int jb = w << 6;
      int jend = min(64, PRE - jb);
      for (int bit = 0; bit < jend; bit++) {
        int j = jb + bit;
        if (j > i) {
          float ltx = fmaxf(bx1, sx1[j]), lty = fmaxf(by1, sy1[j]);
          float rbx = fminf(bx2, sx2[j]), rby = fminf(by2, sy2[j]);
          float wx = fmaxf(rbx - ltx, 0.0f), wy = fmaxf(rby - lty, 0.0f);
          float inter = wx * wy;
          float denom = ba + sar[j] - inter + 1e-9f;  // same assoc. order as reference
          if (inter / denom > 0.7f) mm |= (1ull << bit);
        }
      }
      mask[((size_t)b * 16 + w) * PRE + i] = mm;      // [b][word][i] -> coalesced store
    }
  }
}

// ---------------- K6: sequential greedy scan, one wave per batch ----------------
__global__ __launch_bounds__(64) void k_scan(const uint64_t* __restrict__ mask,
                                             const uint64_t* __restrict__ validW,
                                             uint64_t* __restrict__ keepW) {
  int b = blockIdx.x, lane = threadIdx.x;
  int wl = (lane < 16) ? lane : 0;
  const uint64_t* mrow = mask + ((size_t)b * 16 + wl) * PRE;
  uint64_t vw = validW[b * 16 + wl];
  uint64_t remv = ~vw;                 // invalid = pre-removed (can't suppress)
  uint64_t pf[8];
#pragma unroll
  for (int p = 0; p < 8; p++) pf[p] = mrow[p];
  for (int i = 0; i < PRE; i++) {
    uint64_t m = pf[i & 7];
    if (i + 8 < PRE) pf[i & 7] = mrow[i + 8];        // prefetch ring hides L2 latency
    uint64_t rw = __shfl(remv, i >> 6, 64);
    if (!((rw >> (i & 63)) & 1ull)) remv |= m;       // rw is wave-uniform -> no divergence
  }
  if (lane < 16) keepW[b * 16 + lane] = vw & ~remv;
}

// ---------------- K7: rank via popcount prefix + pack + zero-fill ----------------
__global__ __launch_bounds__(256) void k_pack(const uint64_t* __restrict__ keepW,
                                              const float4* __restrict__ bc,
                                              const float* __restrict__ score,
                                              float* __restrict__ out) {
  __shared__ uint64_t kw[16];
  __shared__ unsigned wp[17];
  int b = blockIdx.x, t = threadIdx.x;
  if (t < 16) kw[t] = keepW[b * 16 + t];
  __syncthreads();
  if (t == 0) {
    unsigned s = 0;
    for (int i = 0; i < 16; i++) { wp[i] = s; s += __popcll(kw[i]); }
    wp[16] = s;
  }
  __syncthreads();
  unsigned K = wp[16];
  float4* ob = (float4*)out;                      // boxes: [B][PRE][4]
  float* os = out + (size_t)BB * PRE * 4;         // scores: [B][PRE]
  for (int r = t; r < PRE; r += 256) {
    uint64_t wbits = kw[r >> 6];
    if ((wbits >> (r & 63)) & 1ull) {
      unsigned rank = wp[r >> 6] + (unsigned)__popcll(wbits & ((1ull << (r & 63)) - 1ull));
      ob[(size_t)b * PRE + rank] = bc[(size_t)b * PRE + r];
      os[(size_t)b * PRE + rank] = score[(size_t)b * PRE + r];
    }
  }
  for (int s2 = t; s2 < PRE; s2 += 256) {
    if (s2 >= (int)K) {
      ob[(size_t)b * PRE + s2] = make_float4(0.f, 0.f, 0.f, 0.f);
      os[(size_t)b * PRE + s2] = 0.0f;
    }
  }
}

extern "C" void kernel_launch(void* const* d_in, const int* in_sizes, int n_in,
                              void* d_out, int out_size, void* d_ws, size_t ws_size,
                              hipStream_t stream) {
  const float4* prop = (const float4*)d_in[0];
  const float*  obj  = (const float*)d_in[1];
  const int*    lvls = (const int*)d_in[2];
  const int*    ph   = (const int*)d_in[3];
  const int*    pw   = (const int*)d_in[4];
  unsigned char* ws = (unsigned char*)d_ws;

  unsigned* hist  = (unsigned*)(ws);
  unsigned* cnt   = (unsigned*)(ws + OFF_CNT);
  unsigned* Tarr  = (unsigned*)(ws + OFF_T);
  float*    scale = (float*)(ws + OFF_SCALE);
  uint64_t* cand  = (uint64_t*)(ws + OFF_CAND);
  float*    score = (float*)(ws + OFF_SCORE);
  float4*   bc    = (float4*)(ws + OFF_BC);
  int*      lvlT  = (int*)(ws + OFF_LVL);
  uint64_t* validW= (uint64_t*)(ws + OFF_VALID);
  uint64_t* keepW = (uint64_t*)(ws + OFF_KEEP);
  uint64_t* mask  = (uint64_t*)(ws + OFF_MASK);

  hipMemsetAsync(ws, 0, MEMSET_BYTES, stream);

  int ng = (BB * NN / 4 + 255) / 256;   // 4688 blocks over 1.2M float4s
  k_hist<<<ng, 256, 0, stream>>>((const float4*)obj, hist);
  k_thresh<<<BB, 256, 0, stream>>>(hist, Tarr);
  k_collect<<<ng, 256, 0, stream>>>((const float4*)obj, Tarr, cnt, cand);
  k_sortprep<<<BB, 1024, 0, stream>>>(cand, cnt, prop, lvls, ph, pw,
                                      score, bc, lvlT, validW, scale);
  k_mask<<<dim3(16, BB), 256, 0, stream>>>(bc, lvlT, scale, mask);
  k_scan<<<BB, 64, 0, stream>>>(mask, validW, keepW);
  k_pack<<<BB, 256, 0, stream>>>(keepW, bc, score, (float*)d_out);
}

// Round 3
// 626.646 us; speedup vs baseline: 1.5308x; 1.5308x over previous
//
#include <hip/hip_runtime.h>
#include <stdint.h>

#define BB   16
#define NN   300000
#define PRE  1000
#define NBINS 8192           // 13-bit key histogram
#define KSHIFT 19            // 32-13
#define CAP  2048
#define HSLICES 8            // histogram blocks per batch

// ---------------- workspace layout (bytes) ----------------
constexpr size_t SZ_HIST   = (size_t)BB * NBINS * 4;            // 512 KiB
constexpr size_t OFF_CNT   = SZ_HIST;                           // B u32 (candidate counters)
constexpr size_t OFF_T     = OFF_CNT + 256;                     // B u32 (threshold bin)
constexpr size_t OFF_SCALE = OFF_T + 256;                       // B f32 (max+1)
constexpr size_t OFF_CAND  = OFF_SCALE + 256;                   // B*CAP u64
constexpr size_t OFF_SCORE = OFF_CAND + (size_t)BB * CAP * 8;   // B*PRE f32
constexpr size_t OFF_BC    = OFF_SCORE + (size_t)BB * PRE * 4;  // B*PRE float4 (clipped boxes)
constexpr size_t OFF_LVL   = OFF_BC + (size_t)BB * PRE * 16;    // B*PRE i32
constexpr size_t OFF_VALID = OFF_LVL + (size_t)BB * PRE * 4;    // B*16 u64
constexpr size_t OFF_KEEP  = OFF_VALID + (size_t)BB * 16 * 8;   // B*16 u64
constexpr size_t OFF_MASK  = OFF_KEEP + (size_t)BB * 16 * 8;    // B*16*PRE u64 (2 MB), layout [b][word][i]
constexpr size_t MEMSET_BYTES = OFF_CAND;                       // hist + counters need zeroing

// float -> order-preserving u32 key (ascending)
__device__ __forceinline__ unsigned f2key(float f) {
  unsigned u = __float_as_uint(f);
  return (u & 0x80000000u) ? ~u : (u | 0x80000000u);
}

// ---------------- K1: per-batch 13-bit histogram via LDS ----------------
// grid: (HSLICES, BB). Each block: LDS hist over its slice, sparse flush.
__global__ __launch_bounds__(256) void k_hist(const float4* __restrict__ obj4,
                                              unsigned* __restrict__ hist) {
  __shared__ unsigned lh[NBINS];
  int s = blockIdx.x, b = blockIdx.y, t = threadIdx.x;
  for (int i = t; i < NBINS; i += 256) lh[i] = 0;
  __syncthreads();
  const int W4 = (NN / 4) / HSLICES;          // 9375 float4 per slice
  const float4* base = obj4 + (size_t)b * (NN / 4);
  int lo = s * W4, hi = lo + W4;
  for (int i = lo + t; i < hi; i += 256) {
    float4 v = base[i];
    atomicAdd(&lh[f2key(v.x) >> KSHIFT], 1u);
    atomicAdd(&lh[f2key(v.y) >> KSHIFT], 1u);
    atomicAdd(&lh[f2key(v.z) >> KSHIFT], 1u);
    atomicAdd(&lh[f2key(v.w) >> KSHIFT], 1u);
  }
  __syncthreads();
  unsigned* h = hist + (size_t)b * NBINS;
  for (int i = t; i < NBINS; i += 256) {
    unsigned c = lh[i];
    if (c) atomicAdd(&h[i], c);
  }
}

// ---------------- K2: find per-batch threshold bin (all-LDS scan) ----------------
__global__ __launch_bounds__(256) void k_thresh(const unsigned* __restrict__ hist,
                                                unsigned* __restrict__ Tarr) {
  __shared__ unsigned bins[NBINS];
  __shared__ unsigned part[256];
  int b = blockIdx.x, t = threadIdx.x;
  const uint4* h4 = (const uint4*)(hist + (size_t)b * NBINS);
  uint4* b4 = (uint4*)bins;
  unsigned s = 0;
  for (int j = 0; j < NBINS / 4 / 256; j++) {        // 8 uint4 = 32 bins per thread
    uint4 v = h4[t * (NBINS / 4 / 256) + j];
    b4[t * (NBINS / 4 / 256) + j] = v;
    s += v.x + v.y + v.z + v.w;
  }
  part[t] = s;   // sum of bins [t*32, t*32+32)
  __syncthreads();
  if (t == 0) {
    unsigned run = 0; int c = 255;
    for (; c > 0; c--) { if (run + part[c] >= (unsigned)PRE) break; run += part[c]; }
    unsigned T = 0;
    for (int j = 31; j >= 0; j--) {
      run += bins[c * 32 + j];
      if (run >= (unsigned)PRE) { T = (unsigned)(c * 32 + j); break; }
    }
    Tarr[b] = T;
  }
}

// ---------------- K3: collect candidates >= threshold ----------------
__global__ __launch_bounds__(256) void k_collect(const float4* __restrict__ obj4,
                                                 const unsigned* __restrict__ Tarr,
                                                 unsigned* __restrict__ cnt,
                                                 uint64_t* __restrict__ cand) {
  unsigned g = blockIdx.x * 256u + threadIdx.x;
  if (g >= (BB * NN / 4)) return;
  unsigned b = g / (NN / 4);
  unsigned n0 = (g - b * (NN / 4)) * 4u;
  float4 v = obj4[g];
  unsigned T = Tarr[b];
  float fs[4] = {v.x, v.y, v.z, v.w};
#pragma unroll
  for (int q = 0; q < 4; q++) {
    unsigned key = f2key(fs[q]);
    if ((key >> KSHIFT) >= T) {
      unsigned pos = atomicAdd(&cnt[b], 1u);
      if (pos < CAP)
        cand[(size_t)b * CAP + pos] = ((uint64_t)key << 32) | (unsigned)~(n0 + q);
    }
  }
}

// ---------------- K4: per-batch bitonic sort + clip/valid/scale prep ----------------
__global__ __launch_bounds__(1024) void k_sortprep(
    const uint64_t* __restrict__ cand, const unsigned* __restrict__ cnt,
    const float4* __restrict__ prop, const int* __restrict__ lvls,
    const int* __restrict__ ph, const int* __restrict__ pw,
    float* __restrict__ score, float4* __restrict__ bc, int* __restrict__ lvlT,
    uint64_t* __restrict__ validW, float* __restrict__ scale) {
  __shared__ uint64_t arr[CAP];
  __shared__ float red[16];
  int b = blockIdx.x, t = threadIdx.x;
  unsigned m = cnt[b]; if (m > CAP) m = CAP;
  for (int i = t; i < CAP; i += 1024) arr[i] = (i < (int)m) ? cand[(size_t)b * CAP + i] : 0ull;
  __syncthreads();
  for (unsigned k = 2; k <= CAP; k <<= 1) {
    for (unsigned j = k >> 1; j > 0; j >>= 1) {
      for (unsigned i = t; i < CAP; i += 1024) {
        unsigned ixj = i ^ j;
        if (ixj > i) {
          uint64_t a = arr[i], c2 = arr[ixj];
          bool sw = ((i & k) == 0) ? (a > c2) : (a < c2);
          if (sw) { arr[i] = c2; arr[ixj] = a; }
        }
      }
      __syncthreads();
    }
  }
  float W = (float)(*pw), H = (float)(*ph);
  float lm = 0.0f; bool valid = false;
  if (t < PRE) {
    uint64_t c = arr[CAP - 1 - t];          // rank t (descending, ties by lower idx)
    unsigned key = (unsigned)(c >> 32);
    unsigned idx = ~((unsigned)c);
    if (idx >= NN) idx = 0;                 // crash-proof clamp (never hit in valid data)
    unsigned ub = (key & 0x80000000u) ? (key & 0x7FFFFFFFu) : ~key;
    float4 p = prop[(size_t)b * NN + idx];
    float x1 = fminf(fmaxf(p.x, 0.0f), W);
    float y1 = fminf(fmaxf(p.y, 0.0f), H);
    float x2 = fminf(fmaxf(p.z, 0.0f), W);
    float y2 = fminf(fmaxf(p.w, 0.0f), H);
    valid = ((x2 - x1) > 0.001f) && ((y2 - y1) > 0.001f);
    bc[(size_t)b * PRE + t] = make_float4(x1, y1, x2, y2);
    score[b * PRE + t] = __uint_as_float(ub);
    lvlT[b * PRE + t] = lvls[idx];
    lm = fmaxf(fmaxf(x1, y1), fmaxf(x2, y2));
  }
  uint64_t bal = __ballot(valid);
  if ((t & 63) == 0) validW[b * 16 + (t >> 6)] = bal;
  for (int o = 32; o > 0; o >>= 1) lm = fmaxf(lm, __shfl_xor(lm, o, 64));
  if ((t & 63) == 0) red[t >> 6] = lm;
  __syncthreads();
  if (t == 0) {
    float mm = red[0];
    for (int i = 1; i < 16; i++) mm = fmaxf(mm, red[i]);
    scale[b] = mm + 1.0f;                   // jnp.max(bc) + 1.0
  }
}

// ---------------- K5: suppression bitmask (iou(i,j)>0.7 & j>i) ----------------
__global__ __launch_bounds__(256) void k_mask(const float4* __restrict__ bc,
                                              const int* __restrict__ lvlT,
                                              const float* __restrict__ scale,
                                              uint64_t* __restrict__ mask) {
  __shared__ float sx1[PRE], sy1[PRE], sx2[PRE], sy2[PRE], sar[PRE];
  int tile = blockIdx.x, b = blockIdx.y, t = threadIdx.x;
  float sc = scale[b];
  for (int i = t; i < PRE; i += 256) {
    float4 v = bc[(size_t)b * PRE + i];
    float off = (float)lvlT[b * PRE + i] * sc;
    float x1 = v.x + off, y1 = v.y + off, x2 = v.z + off, y2 = v.w + off;
    sx1[i] = x1; sy1[i] = y1; sx2[i] = x2; sy2[i] = y2;
    sar[i] = fmaxf(x2 - x1, 0.0f) * fmaxf(y2 - y1, 0.0f);   // area on OFFSET coords (matches ref)
  }
  __syncthreads();
#pragma unroll
  for (int pass = 0; pass < 4; pass++) {
    int tau = t + 256 * pass;
    int w = tau >> 6;                 // wave-uniform word -> LDS broadcast on j reads
    int i = tile * 64 + (tau & 63);   // lane-varying row  -> stride-1 LDS on i reads
    if (i < PRE) {
      float bx1 = sx1[i], by1 = sy1[i], bx2 = sx2[i], by2 = sy2[i], ba = sar[i];
      uint64_t mm = 0;
      int jb = w << 6;
      int jend = min(64, PRE - jb);
      for (int bit = 0; bit < jend; bit++) {
        int j = jb + bit;
        if (j > i) {
          float ltx = fmaxf(bx1, sx1[j]), lty = fmaxf(by1, sy1[j]);
          float rbx = fminf(bx2, sx2[j]), rby = fminf(by2, sy2[j]);
          float wx = fmaxf(rbx - ltx, 0.0f), wy = fmaxf(rby - lty, 0.0f);
          float inter = wx * wy;
          float denom = ba + sar[j] - inter + 1e-9f;  // same assoc. order as reference
          if (inter / denom > 0.7f) mm |= (1ull << bit);
        }
      }
      mask[((size_t)b * 16 + w) * PRE + i] = mm;      // [b][word][i] -> coalesced store
    }
  }
}

// ---------------- K6: sequential greedy scan, one wave per batch ----------------
__global__ __launch_bounds__(64) void k_scan(const uint64_t* __restrict__ mask,
                                             const uint64_t* __restrict__ validW,
                                             uint64_t* __restrict__ keepW) {
  int b = blockIdx.x, lane = threadIdx.x;
  int wl = (lane < 16) ? lane : 0;
  const uint64_t* mrow = mask + ((size_t)b * 16 + wl) * PRE;
  uint64_t vw = validW[b * 16 + wl];
  uint64_t remv = ~vw;                 // invalid = pre-removed (can't suppress)
  uint64_t pf[8];
#pragma unroll
  for (int p = 0; p < 8; p++) pf[p] = mrow[p];
  for (int i = 0; i < PRE; i++) {
    uint64_t m = pf[i & 7];
    if (i + 8 < PRE) pf[i & 7] = mrow[i + 8];        // prefetch ring hides L2 latency
    uint64_t rw = __shfl(remv, i >> 6, 64);
    if (!((rw >> (i & 63)) & 1ull)) remv |= m;       // rw is wave-uniform -> no divergence
  }
  if (lane < 16) keepW[b * 16 + lane] = vw & ~remv;
}

// ---------------- K7: rank via popcount prefix + pack + zero-fill ----------------
__global__ __launch_bounds__(256) void k_pack(const uint64_t* __restrict__ keepW,
                                              const float4* __restrict__ bc,
                                              const float* __restrict__ score,
                                              float* __restrict__ out) {
  __shared__ uint64_t kw[16];
  __shared__ unsigned wp[17];
  int b = blockIdx.x, t = threadIdx.x;
  if (t < 16) kw[t] = keepW[b * 16 + t];
  __syncthreads();
  if (t == 0) {
    unsigned s = 0;
    for (int i = 0; i < 16; i++) { wp[i] = s; s += __popcll(kw[i]); }
    wp[16] = s;
  }
  __syncthreads();
  unsigned K = wp[16];
  float4* ob = (float4*)out;                      // boxes: [B][PRE][4]
  float* os = out + (size_t)BB * PRE * 4;         // scores: [B][PRE]
  for (int r = t; r < PRE; r += 256) {
    uint64_t wbits = kw[r >> 6];
    if ((wbits >> (r & 63)) & 1ull) {
      unsigned rank = wp[r >> 6] + (unsigned)__popcll(wbits & ((1ull << (r & 63)) - 1ull));
      ob[(size_t)b * PRE + rank] = bc[(size_t)b * PRE + r];
      os[(size_t)b * PRE + rank] = score[(size_t)b * PRE + r];
    }
  }
  for (int s2 = t; s2 < PRE; s2 += 256) {
    if (s2 >= (int)K) {
      ob[(size_t)b * PRE + s2] = make_float4(0.f, 0.f, 0.f, 0.f);
      os[(size_t)b * PRE + s2] = 0.0f;
    }
  }
}

extern "C" void kernel_launch(void* const* d_in, const int* in_sizes, int n_in,
                              void* d_out, int out_size, void* d_ws, size_t ws_size,
                              hipStream_t stream) {
  const float4* prop = (const float4*)d_in[0];
  const float*  obj  = (const float*)d_in[1];
  const int*    lvls = (const int*)d_in[2];
  const int*    ph   = (const int*)d_in[3];
  const int*    pw   = (const int*)d_in[4];
  unsigned char* ws = (unsigned char*)d_ws;

  unsigned* hist  = (unsigned*)(ws);
  unsigned* cnt   = (unsigned*)(ws + OFF_CNT);
  unsigned* Tarr  = (unsigned*)(ws + OFF_T);
  float*    scale = (float*)(ws + OFF_SCALE);
  uint64_t* cand  = (uint64_t*)(ws + OFF_CAND);
  float*    score = (float*)(ws + OFF_SCORE);
  float4*   bc    = (float4*)(ws + OFF_BC);
  int*      lvlT  = (int*)(ws + OFF_LVL);
  uint64_t* validW= (uint64_t*)(ws + OFF_VALID);
  uint64_t* keepW = (uint64_t*)(ws + OFF_KEEP);
  uint64_t* mask  = (uint64_t*)(ws + OFF_MASK);

  hipMemsetAsync(ws, 0, MEMSET_BYTES, stream);

  k_hist<<<dim3(HSLICES, BB), 256, 0, stream>>>((const float4*)obj, hist);
  k_thresh<<<BB, 256, 0, stream>>>(hist, Tarr);
  int ng = (BB * NN / 4 + 255) / 256;   // 4688 blocks over 1.2M float4s
  k_collect<<<ng, 256, 0, stream>>>((const float4*)obj, Tarr, cnt, cand);
  k_sortprep<<<BB, 1024, 0, stream>>>(cand, cnt, prop, lvls, ph, pw,
                                      score, bc, lvlT, validW, scale);
  k_mask<<<dim3(16, BB), 256, 0, stream>>>(bc, lvlT, scale, mask);
  k_scan<<<BB, 64, 0, stream>>>(mask, validW, keepW);
  k_pack<<<BB, 256, 0, stream>>>(keepW, bc, score, (float*)d_out);
}

// Round 4
// 391.994 us; speedup vs baseline: 2.4472x; 1.5986x over previous
//
#include <hip/hip_runtime.h>
#include <stdint.h>

#define BB   16
#define NN   300000
#define PRE  1000
#define NBINS 8192           // 13-bit key histogram
#define KSHIFT 19            // 32-13
#define CAP  2048
#define HSLICES 8            // histogram blocks per batch
#define CCHUNK 32            // collect blocks per batch
#define CBUF 1024            // per-block LDS candidate buffer

// ---------------- workspace layout (bytes) ----------------
constexpr size_t SZ_HIST   = (size_t)BB * NBINS * 4;            // 512 KiB
constexpr size_t OFF_CNT   = SZ_HIST;                           // B counters, stride 32 u32 (128B each)
constexpr size_t OFF_T     = OFF_CNT + (size_t)BB * 32 * 4;     // B u32 (threshold bin)
constexpr size_t OFF_SCALE = OFF_T + 256;                       // B f32 (max+1)
constexpr size_t OFF_CAND  = OFF_SCALE + 256;                   // B*CAP u64
constexpr size_t OFF_SCORE = OFF_CAND + (size_t)BB * CAP * 8;   // B*PRE f32
constexpr size_t OFF_BC    = OFF_SCORE + (size_t)BB * PRE * 4;  // B*PRE float4 (clipped boxes)
constexpr size_t OFF_LVL   = OFF_BC + (size_t)BB * PRE * 16;    // B*PRE i32
constexpr size_t OFF_VALID = OFF_LVL + (size_t)BB * PRE * 4;    // B*16 u64
constexpr size_t OFF_KEEP  = OFF_VALID + (size_t)BB * 16 * 8;   // B*16 u64
constexpr size_t OFF_MASK  = OFF_KEEP + (size_t)BB * 16 * 8;    // B*16*PRE u64 (2 MB), layout [b][word][i]
constexpr size_t MEMSET_BYTES = OFF_CAND;                       // hist + counters need zeroing

// float -> order-preserving u32 key (ascending)
__device__ __forceinline__ unsigned f2key(float f) {
  unsigned u = __float_as_uint(f);
  return (u & 0x80000000u) ? ~u : (u | 0x80000000u);
}

// ---------------- K1: per-batch 13-bit histogram via LDS ----------------
// grid: (HSLICES, BB). Each block: LDS hist over its slice, sparse flush.
__global__ __launch_bounds__(256) void k_hist(const float4* __restrict__ obj4,
                                              unsigned* __restrict__ hist) {
  __shared__ unsigned lh[NBINS];
  int s = blockIdx.x, b = blockIdx.y, t = threadIdx.x;
  for (int i = t; i < NBINS; i += 256) lh[i] = 0;
  __syncthreads();
  const int W4 = (NN / 4) / HSLICES;          // 9375 float4 per slice
  const float4* base = obj4 + (size_t)b * (NN / 4);
  int lo = s * W4, hi = lo + W4;
  for (int i = lo + t; i < hi; i += 256) {
    float4 v = base[i];
    atomicAdd(&lh[f2key(v.x) >> KSHIFT], 1u);
    atomicAdd(&lh[f2key(v.y) >> KSHIFT], 1u);
    atomicAdd(&lh[f2key(v.z) >> KSHIFT], 1u);
    atomicAdd(&lh[f2key(v.w) >> KSHIFT], 1u);
  }
  __syncthreads();
  unsigned* h = hist + (size_t)b * NBINS;
  for (int i = t; i < NBINS; i += 256) {
    unsigned c = lh[i];
    if (c) atomicAdd(&h[i], c);
  }
}

// ---------------- K2: find per-batch threshold bin (all-LDS scan) ----------------
__global__ __launch_bounds__(256) void k_thresh(const unsigned* __restrict__ hist,
                                                unsigned* __restrict__ Tarr) {
  __shared__ unsigned bins[NBINS];
  __shared__ unsigned part[256];
  int b = blockIdx.x, t = threadIdx.x;
  const uint4* h4 = (const uint4*)(hist + (size_t)b * NBINS);
  uint4* b4 = (uint4*)bins;
  unsigned s = 0;
  for (int j = 0; j < NBINS / 4 / 256; j++) {        // 8 uint4 = 32 bins per thread
    uint4 v = h4[t * (NBINS / 4 / 256) + j];
    b4[t * (NBINS / 4 / 256) + j] = v;
    s += v.x + v.y + v.z + v.w;
  }
  part[t] = s;   // sum of bins [t*32, t*32+32)
  __syncthreads();
  if (t == 0) {
    unsigned run = 0; int c = 255;
    for (; c > 0; c--) { if (run + part[c] >= (unsigned)PRE) break; run += part[c]; }
    unsigned T = 0;
    for (int j = 31; j >= 0; j--) {
      run += bins[c * 32 + j];
      if (run >= (unsigned)PRE) { T = (unsigned)(c * 32 + j); break; }
    }
    Tarr[b] = T;
  }
}

// ---------------- K3: collect candidates >= threshold (block-aggregated) ----------------
// grid: (CCHUNK, BB). LDS-staged candidates, ONE global atomic per block.
__global__ __launch_bounds__(256) void k_collect(const float4* __restrict__ obj4,
                                                 const unsigned* __restrict__ Tarr,
                                                 unsigned* __restrict__ cnt,
                                                 uint64_t* __restrict__ cand) {
  __shared__ uint64_t buf[CBUF];
  __shared__ unsigned lcnt, gbase;
  int s = blockIdx.x, b = blockIdx.y, t = threadIdx.x;
  if (t == 0) lcnt = 0;
  __syncthreads();
  const int W4 = (NN / 4 + CCHUNK - 1) / CCHUNK;      // 2344
  int lo = s * W4, hi = min(lo + W4, NN / 4);
  unsigned T = Tarr[b];
  const float4* base = obj4 + (size_t)b * (NN / 4);
  for (int i = lo + t; i < hi; i += 256) {
    float4 v = base[i];
    unsigned n0 = (unsigned)i * 4u;
    float fs[4] = {v.x, v.y, v.z, v.w};
#pragma unroll
    for (int q = 0; q < 4; q++) {
      unsigned key = f2key(fs[q]);
      if ((key >> KSHIFT) >= T) {
        unsigned p = atomicAdd(&lcnt, 1u);           // LDS atomic, ~43 hits/block
        if (p < CBUF) buf[p] = ((uint64_t)key << 32) | (unsigned)~(n0 + q);
      }
    }
  }
  __syncthreads();
  unsigned m = lcnt; if (m > CBUF) m = CBUF;
  if (t == 0) gbase = atomicAdd(&cnt[b * 32], m);    // 1 global atomic per block, padded line
  __syncthreads();
  unsigned gb = gbase;
  for (unsigned i = t; i < m; i += 256) {
    unsigned pos = gb + i;
    if (pos < CAP) cand[(size_t)b * CAP + pos] = buf[i];
  }
}

// ---------------- K4: per-batch bitonic sort + clip/valid/scale prep ----------------
__global__ __launch_bounds__(1024) void k_sortprep(
    const uint64_t* __restrict__ cand, const unsigned* __restrict__ cnt,
    const float4* __restrict__ prop, const int* __restrict__ lvls,
    const int* __restrict__ ph, const int* __restrict__ pw,
    float* __restrict__ score, float4* __restrict__ bc, int* __restrict__ lvlT,
    uint64_t* __restrict__ validW, float* __restrict__ scale) {
  __shared__ uint64_t arr[CAP];
  __shared__ float red[16];
  int b = blockIdx.x, t = threadIdx.x;
  unsigned m = cnt[b * 32]; if (m > CAP) m = CAP;
  for (int i = t; i < CAP; i += 1024) arr[i] = (i < (int)m) ? cand[(size_t)b * CAP + i] : 0ull;
  __syncthreads();
  for (unsigned k = 2; k <= CAP; k <<= 1) {
    for (unsigned j = k >> 1; j > 0; j >>= 1) {
      for (unsigned i = t; i < CAP; i += 1024) {
        unsigned ixj = i ^ j;
        if (ixj > i) {
          uint64_t a = arr[i], c2 = arr[ixj];
          bool sw = ((i & k) == 0) ? (a > c2) : (a < c2);
          if (sw) { arr[i] = c2; arr[ixj] = a; }
        }
      }
      __syncthreads();
    }
  }
  float W = (float)(*pw), H = (float)(*ph);
  float lm = 0.0f; bool valid = false;
  if (t < PRE) {
    uint64_t c = arr[CAP - 1 - t];          // rank t (descending, ties by lower idx)
    unsigned key = (unsigned)(c >> 32);
    unsigned idx = ~((unsigned)c);
    if (idx >= NN) idx = 0;                 // crash-proof clamp (never hit in valid data)
    unsigned ub = (key & 0x80000000u) ? (key & 0x7FFFFFFFu) : ~key;
    float4 p = prop[(size_t)b * NN + idx];
    float x1 = fminf(fmaxf(p.x, 0.0f), W);
    float y1 = fminf(fmaxf(p.y, 0.0f), H);
    float x2 = fminf(fmaxf(p.z, 0.0f), W);
    float y2 = fminf(fmaxf(p.w, 0.0f), H);
    valid = ((x2 - x1) > 0.001f) && ((y2 - y1) > 0.001f);
    bc[(size_t)b * PRE + t] = make_float4(x1, y1, x2, y2);
    score[b * PRE + t] = __uint_as_float(ub);
    lvlT[b * PRE + t] = lvls[idx];
    lm = fmaxf(fmaxf(x1, y1), fmaxf(x2, y2));
  }
  uint64_t bal = __ballot(valid);
  if ((t & 63) == 0) validW[b * 16 + (t >> 6)] = bal;
  for (int o = 32; o > 0; o >>= 1) lm = fmaxf(lm, __shfl_xor(lm, o, 64));
  if ((t & 63) == 0) red[t >> 6] = lm;
  __syncthreads();
  if (t == 0) {
    float mm = red[0];
    for (int i = 1; i < 16; i++) mm = fmaxf(mm, red[i]);
    scale[b] = mm + 1.0f;                   // jnp.max(bc) + 1.0
  }
}

// ---------------- K5: suppression bitmask (iou(i,j)>0.7 & j>i) ----------------
__global__ __launch_bounds__(256) void k_mask(const float4* __restrict__ bc,
                                              const int* __restrict__ lvlT,
                                              const float* __restrict__ scale,
                                              uint64_t* __restrict__ mask) {
  __shared__ float sx1[PRE], sy1[PRE], sx2[PRE], sy2[PRE], sar[PRE];
  int tile = blockIdx.x, b = blockIdx.y, t = threadIdx.x;
  float sc = scale[b];
  for (int i = t; i < PRE; i += 256) {
    float4 v = bc[(size_t)b * PRE + i];
    float off = (float)lvlT[b * PRE + i] * sc;
    float x1 = v.x + off, y1 = v.y + off, x2 = v.z + off, y2 = v.w + off;
    sx1[i] = x1; sy1[i] = y1; sx2[i] = x2; sy2[i] = y2;
    sar[i] = fmaxf(x2 - x1, 0.0f) * fmaxf(y2 - y1, 0.0f);   // area on OFFSET coords (matches ref)
  }
  __syncthreads();
#pragma unroll
  for (int pass = 0; pass < 4; pass++) {
    int tau = t + 256 * pass;
    int w = tau >> 6;                 // wave-uniform word -> LDS broadcast on j reads
    int i = tile * 64 + (tau & 63);   // lane-varying row  -> stride-1 LDS on i reads
    if (i < PRE) {
      float bx1 = sx1[i], by1 = sy1[i], bx2 = sx2[i], by2 = sy2[i], ba = sar[i];
      uint64_t mm = 0;
      int jb = w << 6;
      int jend = min(64, PRE - jb);
      for (int bit = 0; bit < jend; bit++) {
        int j = jb + bit;
        if (j > i) {
          float ltx = fmaxf(bx1, sx1[j]), lty = fmaxf(by1, sy1[j]);
          float rbx = fminf(bx2, sx2[j]), rby = fminf(by2, sy2[j]);
          float wx = fmaxf(rbx - ltx, 0.0f), wy = fmaxf(rby - lty, 0.0f);
          float inter = wx * wy;
          float denom = ba + sar[j] - inter + 1e-9f;  // same assoc. order as reference
          if (inter / denom > 0.7f) mm |= (1ull << bit);
        }
      }
      mask[((size_t)b * 16 + w) * PRE + i] = mm;      // [b][word][i] -> coalesced store
    }
  }
}

// ---------------- K6: greedy scan (wave 0) + rank/pack (whole block) ----------------
__global__ __launch_bounds__(256) void k_scanpack(const uint64_t* __restrict__ mask,
                                                  const uint64_t* __restrict__ validW,
                                                  const float4* __restrict__ bc,
                                                  const float* __restrict__ score,
                                                  float* __restrict__ out) {
  __shared__ uint64_t kw[16];
  __shared__ unsigned wp[17];
  int b = blockIdx.x, t = threadIdx.x;
  if (t < 64) {
    int lane = t;
    int wl = (lane < 16) ? lane : 0;
    const uint64_t* mrow = mask + ((size_t)b * 16 + wl) * PRE;
    uint64_t vw = validW[b * 16 + wl];
    uint64_t remv = ~vw;               // invalid = pre-removed (can't suppress)
    uint64_t pf[8];
#pragma unroll
    for (int p = 0; p < 8; p++) pf[p] = mrow[p];
    for (int i = 0; i < PRE; i++) {
      uint64_t m = pf[i & 7];
      if (i + 8 < PRE) pf[i & 7] = mrow[i + 8];      // prefetch ring hides L2 latency
      uint64_t rw = __shfl(remv, i >> 6, 64);
      if (!((rw >> (i & 63)) & 1ull)) remv |= m;     // rw wave-uniform -> no divergence
    }
    if (lane < 16) kw[lane] = vw & ~remv;
  }
  __syncthreads();
  if (t == 0) {
    unsigned s = 0;
    for (int i = 0; i < 16; i++) { wp[i] = s; s += __popcll(kw[i]); }
    wp[16] = s;
  }
  __syncthreads();
  unsigned K = wp[16];
  float4* ob = (float4*)out;                      // boxes: [B][PRE][4]
  float* os = out + (size_t)BB * PRE * 4;         // scores: [B][PRE]
  for (int r = t; r < PRE; r += 256) {
    uint64_t wbits = kw[r >> 6];
    if ((wbits >> (r & 63)) & 1ull) {
      unsigned rank = wp[r >> 6] + (unsigned)__popcll(wbits & ((1ull << (r & 63)) - 1ull));
      ob[(size_t)b * PRE + rank] = bc[(size_t)b * PRE + r];
      os[(size_t)b * PRE + rank] = score[(size_t)b * PRE + r];
    }
  }
  for (int s2 = t; s2 < PRE; s2 += 256) {
    if (s2 >= (int)K) {
      ob[(size_t)b * PRE + s2] = make_float4(0.f, 0.f, 0.f, 0.f);
      os[(size_t)b * PRE + s2] = 0.0f;
    }
  }
}

extern "C" void kernel_launch(void* const* d_in, const int* in_sizes, int n_in,
                              void* d_out, int out_size, void* d_ws, size_t ws_size,
                              hipStream_t stream) {
  const float4* prop = (const float4*)d_in[0];
  const float*  obj  = (const float*)d_in[1];
  const int*    lvls = (const int*)d_in[2];
  const int*    ph   = (const int*)d_in[3];
  const int*    pw   = (const int*)d_in[4];
  unsigned char* ws = (unsigned char*)d_ws;

  unsigned* hist  = (unsigned*)(ws);
  unsigned* cnt   = (unsigned*)(ws + OFF_CNT);
  unsigned* Tarr  = (unsigned*)(ws + OFF_T);
  float*    scale = (float*)(ws + OFF_SCALE);
  uint64_t* cand  = (uint64_t*)(ws + OFF_CAND);
  float*    score = (float*)(ws + OFF_SCORE);
  float4*   bc    = (float4*)(ws + OFF_BC);
  int*      lvlT  = (int*)(ws + OFF_LVL);
  uint64_t* validW= (uint64_t*)(ws + OFF_VALID);
  uint64_t* keepW = (uint64_t*)(ws + OFF_KEEP);   // unused now (kept in layout)
  (void)keepW;
  uint64_t* mask  = (uint64_t*)(ws + OFF_MASK);

  hipMemsetAsync(ws, 0, MEMSET_BYTES, stream);

  k_hist<<<dim3(HSLICES, BB), 256, 0, stream>>>((const float4*)obj, hist);
  k_thresh<<<BB, 256, 0, stream>>>(hist, Tarr);
  k_collect<<<dim3(CCHUNK, BB), 256, 0, stream>>>((const float4*)obj, Tarr, cnt, cand);
  k_sortprep<<<BB, 1024, 0, stream>>>(cand, cnt, prop, lvls, ph, pw,
                                      score, bc, lvlT, validW, scale);
  k_mask<<<dim3(16, BB), 256, 0, stream>>>(bc, lvlT, scale, mask);
  k_scanpack<<<BB, 256, 0, stream>>>(mask, validW, bc, score, (float*)d_out);
}

// Round 5
// 286.602 us; speedup vs baseline: 3.3471x; 1.3677x over previous
//
#include <hip/hip_runtime.h>
#include <stdint.h>

#define BB   16
#define NN   300000
#define PRE  1000
#define NBINS 8192           // 13-bit key histogram
#define KSHIFT 19            // 32-13
#define CAP  2048
#define HSLICES 8            // histogram blocks per batch
#define CCHUNK 32            // collect blocks per batch
#define CBUF 1024            // per-block LDS candidate buffer

// ---------------- workspace layout (bytes) ----------------
constexpr size_t SZ_HIST   = (size_t)BB * NBINS * 4;            // 512 KiB
constexpr size_t OFF_CNT   = SZ_HIST;                           // B counters, stride 32 u32 (128B each)
constexpr size_t OFF_T     = OFF_CNT + (size_t)BB * 32 * 4;     // B u32 (threshold bin)
constexpr size_t OFF_SCALE = OFF_T + 256;                       // B f32 (max+1)
constexpr size_t OFF_CAND  = OFF_SCALE + 256;                   // B*CAP u64
constexpr size_t OFF_SCORE = OFF_CAND + (size_t)BB * CAP * 8;   // B*PRE f32
constexpr size_t OFF_BC    = OFF_SCORE + (size_t)BB * PRE * 4;  // B*PRE float4 (clipped boxes)
constexpr size_t OFF_LVL   = OFF_BC + (size_t)BB * PRE * 16;    // B*PRE i32
constexpr size_t OFF_VALID = OFF_LVL + (size_t)BB * PRE * 4;    // B*16 u64
constexpr size_t OFF_KEEP  = OFF_VALID + (size_t)BB * 16 * 8;   // B*16 u64
constexpr size_t OFF_MASK  = OFF_KEEP + (size_t)BB * 16 * 8;    // B*16*PRE u64 (2 MB), layout [b][word][i]
constexpr size_t MEMSET_BYTES = OFF_CAND;                       // hist + counters need zeroing

// float -> order-preserving u32 key (ascending)
__device__ __forceinline__ unsigned f2key(float f) {
  unsigned u = __float_as_uint(f);
  return (u & 0x80000000u) ? ~u : (u | 0x80000000u);
}

// ---------------- K1: per-batch 13-bit histogram via LDS ----------------
// grid: (HSLICES, BB). Each block: LDS hist over its slice, sparse flush.
__global__ __launch_bounds__(256) void k_hist(const float4* __restrict__ obj4,
                                              unsigned* __restrict__ hist) {
  __shared__ unsigned lh[NBINS];
  int s = blockIdx.x, b = blockIdx.y, t = threadIdx.x;
  for (int i = t; i < NBINS; i += 256) lh[i] = 0;
  __syncthreads();
  const int W4 = (NN / 4) / HSLICES;          // 9375 float4 per slice
  const float4* base = obj4 + (size_t)b * (NN / 4);
  int lo = s * W4, hi = lo + W4;
  for (int i = lo + t; i < hi; i += 256) {
    float4 v = base[i];
    atomicAdd(&lh[f2key(v.x) >> KSHIFT], 1u);
    atomicAdd(&lh[f2key(v.y) >> KSHIFT], 1u);
    atomicAdd(&lh[f2key(v.z) >> KSHIFT], 1u);
    atomicAdd(&lh[f2key(v.w) >> KSHIFT], 1u);
  }
  __syncthreads();
  unsigned* h = hist + (size_t)b * NBINS;
  for (int i = t; i < NBINS; i += 256) {
    unsigned c = lh[i];
    if (c) atomicAdd(&h[i], c);
  }
}

// ---------------- K2: find per-batch threshold bin (all-LDS scan) ----------------
__global__ __launch_bounds__(256) void k_thresh(const unsigned* __restrict__ hist,
                                                unsigned* __restrict__ Tarr) {
  __shared__ unsigned bins[NBINS];
  __shared__ unsigned part[256];
  int b = blockIdx.x, t = threadIdx.x;
  const uint4* h4 = (const uint4*)(hist + (size_t)b * NBINS);
  uint4* b4 = (uint4*)bins;
  unsigned s = 0;
  for (int j = 0; j < NBINS / 4 / 256; j++) {        // 8 uint4 = 32 bins per thread
    uint4 v = h4[t * (NBINS / 4 / 256) + j];
    b4[t * (NBINS / 4 / 256) + j] = v;
    s += v.x + v.y + v.z + v.w;
  }
  part[t] = s;   // sum of bins [t*32, t*32+32)
  __syncthreads();
  if (t == 0) {
    unsigned run = 0; int c = 255;
    for (; c > 0; c--) { if (run + part[c] >= (unsigned)PRE) break; run += part[c]; }
    unsigned T = 0;
    for (int j = 31; j >= 0; j--) {
      run += bins[c * 32 + j];
      if (run >= (unsigned)PRE) { T = (unsigned)(c * 32 + j); break; }
    }
    Tarr[b] = T;
  }
}

// ---------------- K3: collect candidates >= threshold (block-aggregated) ----------------
// grid: (CCHUNK, BB). LDS-staged candidates, ONE global atomic per block.
__global__ __launch_bounds__(256) void k_collect(const float4* __restrict__ obj4,
                                                 const unsigned* __restrict__ Tarr,
                                                 unsigned* __restrict__ cnt,
                                                 uint64_t* __restrict__ cand) {
  __shared__ uint64_t buf[CBUF];
  __shared__ unsigned lcnt, gbase;
  int s = blockIdx.x, b = blockIdx.y, t = threadIdx.x;
  if (t == 0) lcnt = 0;
  __syncthreads();
  const int W4 = (NN / 4 + CCHUNK - 1) / CCHUNK;      // 2344
  int lo = s * W4, hi = min(lo + W4, NN / 4);
  unsigned T = Tarr[b];
  const float4* base = obj4 + (size_t)b * (NN / 4);
  for (int i = lo + t; i < hi; i += 256) {
    float4 v = base[i];
    unsigned n0 = (unsigned)i * 4u;
    float fs[4] = {v.x, v.y, v.z, v.w};
#pragma unroll
    for (int q = 0; q < 4; q++) {
      unsigned key = f2key(fs[q]);
      if ((key >> KSHIFT) >= T) {
        unsigned p = atomicAdd(&lcnt, 1u);           // LDS atomic, ~43 hits/block
        if (p < CBUF) buf[p] = ((uint64_t)key << 32) | (unsigned)~(n0 + q);
      }
    }
  }
  __syncthreads();
  unsigned m = lcnt; if (m > CBUF) m = CBUF;
  if (t == 0) gbase = atomicAdd(&cnt[b * 32], m);    // 1 global atomic per block, padded line
  __syncthreads();
  unsigned gb = gbase;
  for (unsigned i = t; i < m; i += 256) {
    unsigned pos = gb + i;
    if (pos < CAP) cand[(size_t)b * CAP + pos] = buf[i];
  }
}

// ---------------- K4: per-batch bitonic sort + clip/valid/scale prep ----------------
__global__ __launch_bounds__(1024) void k_sortprep(
    const uint64_t* __restrict__ cand, const unsigned* __restrict__ cnt,
    const float4* __restrict__ prop, const int* __restrict__ lvls,
    const int* __restrict__ ph, const int* __restrict__ pw,
    float* __restrict__ score, float4* __restrict__ bc, int* __restrict__ lvlT,
    uint64_t* __restrict__ validW, float* __restrict__ scale) {
  __shared__ uint64_t arr[CAP];
  __shared__ float red[16];
  int b = blockIdx.x, t = threadIdx.x;
  unsigned m = cnt[b * 32]; if (m > CAP) m = CAP;
  for (int i = t; i < CAP; i += 1024) arr[i] = (i < (int)m) ? cand[(size_t)b * CAP + i] : 0ull;
  __syncthreads();
  for (unsigned k = 2; k <= CAP; k <<= 1) {
    for (unsigned j = k >> 1; j > 0; j >>= 1) {
      for (unsigned i = t; i < CAP; i += 1024) {
        unsigned ixj = i ^ j;
        if (ixj > i) {
          uint64_t a = arr[i], c2 = arr[ixj];
          bool sw = ((i & k) == 0) ? (a > c2) : (a < c2);
          if (sw) { arr[i] = c2; arr[ixj] = a; }
        }
      }
      __syncthreads();
    }
  }
  float W = (float)(*pw), H = (float)(*ph);
  float lm = 0.0f; bool valid = false;
  if (t < PRE) {
    uint64_t c = arr[CAP - 1 - t];          // rank t (descending, ties by lower idx)
    unsigned key = (unsigned)(c >> 32);
    unsigned idx = ~((unsigned)c);
    if (idx >= NN) idx = 0;                 // crash-proof clamp (never hit in valid data)
    unsigned ub = (key & 0x80000000u) ? (key & 0x7FFFFFFFu) : ~key;
    float4 p = prop[(size_t)b * NN + idx];
    float x1 = fminf(fmaxf(p.x, 0.0f), W);
    float y1 = fminf(fmaxf(p.y, 0.0f), H);
    float x2 = fminf(fmaxf(p.z, 0.0f), W);
    float y2 = fminf(fmaxf(p.w, 0.0f), H);
    valid = ((x2 - x1) > 0.001f) && ((y2 - y1) > 0.001f);
    bc[(size_t)b * PRE + t] = make_float4(x1, y1, x2, y2);
    score[b * PRE + t] = __uint_as_float(ub);
    lvlT[b * PRE + t] = lvls[idx];
    lm = fmaxf(fmaxf(x1, y1), fmaxf(x2, y2));
  }
  uint64_t bal = __ballot(valid);
  if ((t & 63) == 0) validW[b * 16 + (t >> 6)] = bal;
  for (int o = 32; o > 0; o >>= 1) lm = fmaxf(lm, __shfl_xor(lm, o, 64));
  if ((t & 63) == 0) red[t >> 6] = lm;
  __syncthreads();
  if (t == 0) {
    float mm = red[0];
    for (int i = 1; i < 16; i++) mm = fmaxf(mm, red[i]);
    scale[b] = mm + 1.0f;                   // jnp.max(bc) + 1.0
  }
}

// ---------------- K5: suppression bitmask (iou(i,j)>0.7 & j>i) ----------------
__global__ __launch_bounds__(256) void k_mask(const float4* __restrict__ bc,
                                              const int* __restrict__ lvlT,
                                              const float* __restrict__ scale,
                                              uint64_t* __restrict__ mask) {
  __shared__ float sx1[PRE], sy1[PRE], sx2[PRE], sy2[PRE], sar[PRE];
  int tile = blockIdx.x, b = blockIdx.y, t = threadIdx.x;
  float sc = scale[b];
  for (int i = t; i < PRE; i += 256) {
    float4 v = bc[(size_t)b * PRE + i];
    float off = (float)lvlT[b * PRE + i] * sc;
    float x1 = v.x + off, y1 = v.y + off, x2 = v.z + off, y2 = v.w + off;
    sx1[i] = x1; sy1[i] = y1; sx2[i] = x2; sy2[i] = y2;
    sar[i] = fmaxf(x2 - x1, 0.0f) * fmaxf(y2 - y1, 0.0f);   // area on OFFSET coords (matches ref)
  }
  __syncthreads();
#pragma unroll
  for (int pass = 0; pass < 4; pass++) {
    int tau = t + 256 * pass;
    int w = tau >> 6;                 // wave-uniform word -> LDS broadcast on j reads
    int i = tile * 64 + (tau & 63);   // lane-varying row  -> stride-1 LDS on i reads
    if (i < PRE) {
      float bx1 = sx1[i], by1 = sy1[i], bx2 = sx2[i], by2 = sy2[i], ba = sar[i];
      uint64_t mm = 0;
      int jb = w << 6;
      int jend = min(64, PRE - jb);
      for (int bit = 0; bit < jend; bit++) {
        int j = jb + bit;
        if (j > i) {
          float ltx = fmaxf(bx1, sx1[j]), lty = fmaxf(by1, sy1[j]);
          float rbx = fminf(bx2, sx2[j]), rby = fminf(by2, sy2[j]);
          float wx = fmaxf(rbx - ltx, 0.0f), wy = fmaxf(rby - lty, 0.0f);
          float inter = wx * wy;
          float denom = ba + sar[j] - inter + 1e-9f;  // same assoc. order as reference
          if (inter / denom > 0.7f) mm |= (1ull << bit);
        }
      }
      mask[((size_t)b * 16 + w) * PRE + i] = mm;      // [b][word][i] -> coalesced store
    }
  }
}

// ---------------- K6: greedy scan (wave 0) + rank/pack (whole block) ----------------
// Prefetch ring uses NAMED registers (pf0..pf7): dynamic register-array indexing
// forced scratch round-trips onto the serial chain (~408 cy/iter measured r4).
__global__ __launch_bounds__(256) void k_scanpack(const uint64_t* __restrict__ mask,
                                                  const uint64_t* __restrict__ validW,
                                                  const float4* __restrict__ bc,
                                                  const float* __restrict__ score,
                                                  float* __restrict__ out) {
  __shared__ uint64_t kw[16];
  __shared__ unsigned wp[17];
  int b = blockIdx.x, t = threadIdx.x;
  if (t < 64) {
    int lane = t;
    int wl = (lane < 16) ? lane : 0;
    const uint64_t* mrow = mask + ((size_t)b * 16 + wl) * PRE;
    uint64_t vw = validW[b * 16 + wl];
    uint64_t remv = ~vw;               // invalid = pre-removed (can't suppress)
    uint64_t pf0 = mrow[0], pf1 = mrow[1], pf2 = mrow[2], pf3 = mrow[3];
    uint64_t pf4 = mrow[4], pf5 = mrow[5], pf6 = mrow[6], pf7 = mrow[7];
#define SCAN_STEP(K, PF)                                            \
    {                                                               \
      int i = i8 + K;                                               \
      uint64_t m = PF;                                              \
      if (i + 8 < PRE) PF = mrow[i + 8];                            \
      uint64_t rw = __shfl(remv, i >> 6, 64);                       \
      if (!((rw >> (i & 63)) & 1ull)) remv |= m;                    \
    }
    for (int i8 = 0; i8 < PRE; i8 += 8) {       // PRE = 125 * 8
      SCAN_STEP(0, pf0) SCAN_STEP(1, pf1) SCAN_STEP(2, pf2) SCAN_STEP(3, pf3)
      SCAN_STEP(4, pf4) SCAN_STEP(5, pf5) SCAN_STEP(6, pf6) SCAN_STEP(7, pf7)
    }
#undef SCAN_STEP
    if (lane < 16) kw[lane] = vw & ~remv;
  }
  __syncthreads();
  if (t == 0) {
    unsigned s = 0;
    for (int i = 0; i < 16; i++) { wp[i] = s; s += __popcll(kw[i]); }
    wp[16] = s;
  }
  __syncthreads();
  unsigned K = wp[16];
  float4* ob = (float4*)out;                      // boxes: [B][PRE][4]
  float* os = out + (size_t)BB * PRE * 4;         // scores: [B][PRE]
  for (int r = t; r < PRE; r += 256) {
    uint64_t wbits = kw[r >> 6];
    if ((wbits >> (r & 63)) & 1ull) {
      unsigned rank = wp[r >> 6] + (unsigned)__popcll(wbits & ((1ull << (r & 63)) - 1ull));
      ob[(size_t)b * PRE + rank] = bc[(size_t)b * PRE + r];
      os[(size_t)b * PRE + rank] = score[(size_t)b * PRE + r];
    }
  }
  for (int s2 = t; s2 < PRE; s2 += 256) {
    if (s2 >= (int)K) {
      ob[(size_t)b * PRE + s2] = make_float4(0.f, 0.f, 0.f, 0.f);
      os[(size_t)b * PRE + s2] = 0.0f;
    }
  }
}

extern "C" void kernel_launch(void* const* d_in, const int* in_sizes, int n_in,
                              void* d_out, int out_size, void* d_ws, size_t ws_size,
                              hipStream_t stream) {
  const float4* prop = (const float4*)d_in[0];
  const float*  obj  = (const float*)d_in[1];
  const int*    lvls = (const int*)d_in[2];
  const int*    ph   = (const int*)d_in[3];
  const int*    pw   = (const int*)d_in[4];
  unsigned char* ws = (unsigned char*)d_ws;

  unsigned* hist  = (unsigned*)(ws);
  unsigned* cnt   = (unsigned*)(ws + OFF_CNT);
  unsigned* Tarr  = (unsigned*)(ws + OFF_T);
  float*    scale = (float*)(ws + OFF_SCALE);
  uint64_t* cand  = (uint64_t*)(ws + OFF_CAND);
  float*    score = (float*)(ws + OFF_SCORE);
  float4*   bc    = (float4*)(ws + OFF_BC);
  int*      lvlT  = (int*)(ws + OFF_LVL);
  uint64_t* validW= (uint64_t*)(ws + OFF_VALID);
  uint64_t* mask  = (uint64_t*)(ws + OFF_MASK);

  hipMemsetAsync(ws, 0, MEMSET_BYTES, stream);

  k_hist<<<dim3(HSLICES, BB), 256, 0, stream>>>((const float4*)obj, hist);
  k_thresh<<<BB, 256, 0, stream>>>(hist, Tarr);
  k_collect<<<dim3(CCHUNK, BB), 256, 0, stream>>>((const float4*)obj, Tarr, cnt, cand);
  k_sortprep<<<BB, 1024, 0, stream>>>(cand, cnt, prop, lvls, ph, pw,
                                      score, bc, lvlT, validW, scale);
  k_mask<<<dim3(16, BB), 256, 0, stream>>>(bc, lvlT, scale, mask);
  k_scanpack<<<BB, 256, 0, stream>>>(mask, validW, bc, score, (float*)d_out);
}

// Round 6
// 271.385 us; speedup vs baseline: 3.5348x; 1.0561x over previous
//
#include <hip/hip_runtime.h>
#include <stdint.h>

#define BB   16
#define NN   300000
#define PRE  1000
#define NBINS 8192           // 13-bit key histogram
#define KSHIFT 19            // 32-13
#define CAP  2048
#define HS   8               // histogram slices per batch
#define CCHUNK 64            // collect blocks per batch
#define CBUF 1024            // per-block LDS candidate buffer

// ---------------- workspace layout (bytes) ----------------
constexpr size_t SZ_HIST   = (size_t)BB * HS * NBINS * 2;       // 2 MiB (u16 per-slice)
constexpr size_t OFF_CNT   = SZ_HIST;                           // B counters, stride 32 u32 (128B each)
constexpr size_t OFF_T     = OFF_CNT + (size_t)BB * 32 * 4;     // B u32 (threshold bin)
constexpr size_t OFF_SCALE = OFF_T + 256;                       // B f32 (max+1)
constexpr size_t OFF_CAND  = OFF_SCALE + 256;                   // B*CAP u64
constexpr size_t OFF_SCORE = OFF_CAND + (size_t)BB * CAP * 8;   // B*PRE f32
constexpr size_t OFF_BC    = OFF_SCORE + (size_t)BB * PRE * 4;  // B*PRE float4 (clipped boxes)
constexpr size_t OFF_LVL   = OFF_BC + (size_t)BB * PRE * 16;    // B*PRE i32
constexpr size_t OFF_VALID = OFF_LVL + (size_t)BB * PRE * 4;    // B*16 u64
constexpr size_t OFF_MASK  = OFF_VALID + (size_t)BB * 16 * 8;   // B*16*PRE u64 (2 MB), [b][word][i]

// float -> order-preserving u32 key (ascending)
__device__ __forceinline__ unsigned f2key(float f) {
  unsigned u = __float_as_uint(f);
  return (u & 0x80000000u) ? ~u : (u | 0x80000000u);
}

// ---------------- K1: per-batch per-slice 13-bit histogram, LDS, plain-store flush ----
// grid: (HS, BB), 1024 threads (16 waves -> latency hiding). NO global atomics.
__global__ __launch_bounds__(1024) void k_hist(const float4* __restrict__ obj4,
                                               uint16_t* __restrict__ hist16) {
  __shared__ unsigned lh[NBINS];
  int s = blockIdx.x, b = blockIdx.y, t = threadIdx.x;
  for (int i = t; i < NBINS; i += 1024) lh[i] = 0;
  __syncthreads();
  const int W4 = (NN / 4) / HS;               // 9375 float4 per slice
  const float4* base = obj4 + (size_t)b * (NN / 4) + (size_t)s * W4;
  for (int i = t; i < W4; i += 1024) {
    float4 v = base[i];
    atomicAdd(&lh[f2key(v.x) >> KSHIFT], 1u);
    atomicAdd(&lh[f2key(v.y) >> KSHIFT], 1u);
    atomicAdd(&lh[f2key(v.z) >> KSHIFT], 1u);
    atomicAdd(&lh[f2key(v.w) >> KSHIFT], 1u);
  }
  __syncthreads();
  uint16_t* h = hist16 + ((size_t)b * HS + s) * NBINS;
  for (int i = t; i < NBINS; i += 1024) {
    unsigned c = lh[i];
    h[i] = (uint16_t)(c > 65535u ? 65535u : c);   // saturate (degenerate data only)
  }
}

// ---------------- K2: threshold bin — slice-sum + parallel suffix-scan pick --------
// Also zeroes cnt[b] (runs before k_collect -> no memset dispatch needed).
__global__ __launch_bounds__(256) void k_thresh(const uint16_t* __restrict__ hist16,
                                                unsigned* __restrict__ Tarr,
                                                unsigned* __restrict__ cnt) {
  __shared__ unsigned wtot[4];
  __shared__ unsigned selChunk, runAbove;
  __shared__ unsigned fb[32];
  int b = blockIdx.x, t = threadIdx.x;
  const uint16_t* hb = hist16 + (size_t)b * HS * NBINS;
  // thread t sums bins [t*32, t*32+32) across HS slices (u16 pairs via uint4)
  unsigned tot = 0;
  for (int s = 0; s < HS; s++) {
    const uint4* p4 = (const uint4*)(hb + (size_t)s * NBINS + t * 32);
#pragma unroll
    for (int j = 0; j < 4; j++) {
      uint4 v = p4[j];
      tot += (v.x & 0xffff) + (v.x >> 16) + (v.y & 0xffff) + (v.y >> 16)
           + (v.z & 0xffff) + (v.z >> 16) + (v.w & 0xffff) + (v.w >> 16);
    }
  }
  // wave-level inclusive suffix scan of chunk sums
  int lane = t & 63, w = t >> 6;
  unsigned sfx = tot;
  for (int off = 1; off < 64; off <<= 1) {
    unsigned o = __shfl_down(sfx, off, 64);
    sfx += (lane + off < 64) ? o : 0u;
  }
  if (lane == 0) wtot[w] = sfx;               // wave total
  __syncthreads();
  unsigned tail = 0;
  for (int ww = w + 1; ww < 4; ww++) tail += wtot[ww];
  unsigned S = sfx + tail;                    // suffix sum over chunks >= t
  // unique chunk: S >= PRE and S - tot < PRE
  if ((S >= (unsigned)PRE) && (S - tot < (unsigned)PRE)) { selChunk = t; runAbove = S - tot; }
  if (t == 0) cnt[b * 32] = 0;                // init collect counter
  __syncthreads();
  unsigned c = selChunk, ra = runAbove;
  if (t < 32) {
    unsigned bsum = 0;
    for (int s = 0; s < HS; s++) bsum += hb[(size_t)s * NBINS + c * 32 + t];
    fb[t] = bsum;
  }
  __syncthreads();
  if (t == 0) {
    unsigned run = ra, T = 0;
    for (int j = 31; j >= 0; j--) {
      run += fb[j];
      if (run >= (unsigned)PRE) { T = c * 32 + (unsigned)j; break; }
    }
    Tarr[b] = T;
  }
}

// ---------------- K3: collect candidates >= threshold (block-aggregated) ----------
// grid: (CCHUNK, BB). LDS-staged, ONE global atomic per block.
__global__ __launch_bounds__(256) void k_collect(const float4* __restrict__ obj4,
                                                 const unsigned* __restrict__ Tarr,
                                                 unsigned* __restrict__ cnt,
                                                 uint64_t* __restrict__ cand) {
  __shared__ uint64_t buf[CBUF];
  __shared__ unsigned lcnt, gbase;
  int s = blockIdx.x, b = blockIdx.y, t = threadIdx.x;
  if (t == 0) lcnt = 0;
  __syncthreads();
  const int W4 = (NN / 4 + CCHUNK - 1) / CCHUNK;      // 1172
  int lo = s * W4, hi = min(lo + W4, NN / 4);
  unsigned T = Tarr[b];
  const float4* base = obj4 + (size_t)b * (NN / 4);
  for (int i = lo + t; i < hi; i += 256) {
    float4 v = base[i];
    unsigned n0 = (unsigned)i * 4u;
    float fs[4] = {v.x, v.y, v.z, v.w};
#pragma unroll
    for (int q = 0; q < 4; q++) {
      unsigned key = f2key(fs[q]);
      if ((key >> KSHIFT) >= T) {
        unsigned p = atomicAdd(&lcnt, 1u);
        if (p < CBUF) buf[p] = ((uint64_t)key << 32) | (unsigned)~(n0 + q);
      }
    }
  }
  __syncthreads();
  unsigned m = lcnt; if (m > CBUF) m = CBUF;
  if (t == 0) gbase = atomicAdd(&cnt[b * 32], m);
  __syncthreads();
  unsigned gb = gbase;
  for (unsigned i = t; i < m; i += 256) {
    unsigned pos = gb + i;
    if (pos < CAP) cand[(size_t)b * CAP + pos] = buf[i];
  }
}

// ---------------- K4: per-batch bitonic sort + clip/valid/scale prep ----------------
__global__ __launch_bounds__(1024) void k_sortprep(
    const uint64_t* __restrict__ cand, const unsigned* __restrict__ cnt,
    const float4* __restrict__ prop, const int* __restrict__ lvls,
    const int* __restrict__ ph, const int* __restrict__ pw,
    float* __restrict__ score, float4* __restrict__ bc, int* __restrict__ lvlT,
    uint64_t* __restrict__ validW, float* __restrict__ scale) {
  __shared__ uint64_t arr[CAP];
  __shared__ float red[16];
  int b = blockIdx.x, t = threadIdx.x;
  unsigned m = cnt[b * 32]; if (m > CAP) m = CAP;
  for (int i = t; i < CAP; i += 1024) arr[i] = (i < (int)m) ? cand[(size_t)b * CAP + i] : 0ull;
  __syncthreads();
  for (unsigned k = 2; k <= CAP; k <<= 1) {
    for (unsigned j = k >> 1; j > 0; j >>= 1) {
      for (unsigned i = t; i < CAP; i += 1024) {
        unsigned ixj = i ^ j;
        if (ixj > i) {
          uint64_t a = arr[i], c2 = arr[ixj];
          bool sw = ((i & k) == 0) ? (a > c2) : (a < c2);
          if (sw) { arr[i] = c2; arr[ixj] = a; }
        }
      }
      __syncthreads();
    }
  }
  float W = (float)(*pw), H = (float)(*ph);
  float lm = 0.0f; bool valid = false;
  if (t < PRE) {
    uint64_t c = arr[CAP - 1 - t];          // rank t (descending, ties by lower idx)
    unsigned key = (unsigned)(c >> 32);
    unsigned idx = ~((unsigned)c);
    if (idx >= NN) idx = 0;                 // crash-proof clamp (never hit in valid data)
    unsigned ub = (key & 0x80000000u) ? (key & 0x7FFFFFFFu) : ~key;
    float4 p = prop[(size_t)b * NN + idx];
    float x1 = fminf(fmaxf(p.x, 0.0f), W);
    float y1 = fminf(fmaxf(p.y, 0.0f), H);
    float x2 = fminf(fmaxf(p.z, 0.0f), W);
    float y2 = fminf(fmaxf(p.w, 0.0f), H);
    valid = ((x2 - x1) > 0.001f) && ((y2 - y1) > 0.001f);
    bc[(size_t)b * PRE + t] = make_float4(x1, y1, x2, y2);
    score[b * PRE + t] = __uint_as_float(ub);
    lvlT[b * PRE + t] = lvls[idx];
    lm = fmaxf(fmaxf(x1, y1), fmaxf(x2, y2));
  }
  uint64_t bal = __ballot(valid);
  if ((t & 63) == 0) validW[b * 16 + (t >> 6)] = bal;
  for (int o = 32; o > 0; o >>= 1) lm = fmaxf(lm, __shfl_xor(lm, o, 64));
  if ((t & 63) == 0) red[t >> 6] = lm;
  __syncthreads();
  if (t == 0) {
    float mm = red[0];
    for (int i = 1; i < 16; i++) mm = fmaxf(mm, red[i]);
    scale[b] = mm + 1.0f;                   // jnp.max(bc) + 1.0
  }
}

// ---------------- K5: suppression bitmask (iou(i,j)>0.7 & j>i) ----------------
__global__ __launch_bounds__(256) void k_mask(const float4* __restrict__ bc,
                                              const int* __restrict__ lvlT,
                                              const float* __restrict__ scale,
                                              uint64_t* __restrict__ mask) {
  __shared__ float sx1[PRE], sy1[PRE], sx2[PRE], sy2[PRE], sar[PRE];
  int tile = blockIdx.x, b = blockIdx.y, t = threadIdx.x;
  float sc = scale[b];
  for (int i = t; i < PRE; i += 256) {
    float4 v = bc[(size_t)b * PRE + i];
    float off = (float)lvlT[b * PRE + i] * sc;
    float x1 = v.x + off, y1 = v.y + off, x2 = v.z + off, y2 = v.w + off;
    sx1[i] = x1; sy1[i] = y1; sx2[i] = x2; sy2[i] = y2;
    sar[i] = fmaxf(x2 - x1, 0.0f) * fmaxf(y2 - y1, 0.0f);   // area on OFFSET coords (matches ref)
  }
  __syncthreads();
#pragma unroll
  for (int pass = 0; pass < 4; pass++) {
    int tau = t + 256 * pass;
    int w = tau >> 6;                 // wave-uniform word -> LDS broadcast on j reads
    int i = tile * 64 + (tau & 63);   // lane-varying row  -> stride-1 LDS on i reads
    if (i < PRE) {
      float bx1 = sx1[i], by1 = sy1[i], bx2 = sx2[i], by2 = sy2[i], ba = sar[i];
      uint64_t mm = 0;
      int jb = w << 6;
      int jend = min(64, PRE - jb);
      for (int bit = 0; bit < jend; bit++) {
        int j = jb + bit;
        if (j > i) {
          float ltx = fmaxf(bx1, sx1[j]), lty = fmaxf(by1, sy1[j]);
          float rbx = fminf(bx2, sx2[j]), rby = fminf(by2, sy2[j]);
          float wx = fmaxf(rbx - ltx, 0.0f), wy = fmaxf(rby - lty, 0.0f);
          float inter = wx * wy;
          float denom = ba + sar[j] - inter + 1e-9f;  // same assoc. order as reference
          if (inter / denom > 0.7f) mm |= (1ull << bit);
        }
      }
      mask[((size_t)b * 16 + w) * PRE + i] = mm;      // [b][word][i] -> coalesced store
    }
  }
}

// ---------------- K6: greedy scan + rank/pack ----------------
// Scan chain is pure VALU: every lane keeps a live copy rwW of the current
// 64-row block's removal word (1 shfl per 64 rows), updated locally via the
// wave-uniform diagonal word mask[b][i>>6][i]. Mask loads ride 8-deep named
// register rings off the dependency chain.
__global__ __launch_bounds__(256) void k_scanpack(const uint64_t* __restrict__ mask,
                                                  const uint64_t* __restrict__ validW,
                                                  const float4* __restrict__ bc,
                                                  const float* __restrict__ score,
                                                  float* __restrict__ out) {
  __shared__ uint64_t kw[16];
  __shared__ unsigned wp[17];
  int b = blockIdx.x, t = threadIdx.x;
  if (t < 64) {
    int lane = t;
    int wl = (lane < 16) ? lane : 0;
    const uint64_t* mcol  = mask + ((size_t)b * 16 + wl) * PRE;  // own column
    const uint64_t* mbase = mask + (size_t)b * 16 * PRE;         // diagonal access
    uint64_t vw = validW[b * 16 + wl];
    uint64_t remv = ~vw;               // invalid = pre-removed (can't suppress)
    uint64_t pm0 = mcol[0], pm1 = mcol[1], pm2 = mcol[2], pm3 = mcol[3];
    uint64_t pm4 = mcol[4], pm5 = mcol[5], pm6 = mcol[6], pm7 = mcol[7];
    uint64_t pd0 = mbase[0], pd1 = mbase[1], pd2 = mbase[2], pd3 = mbase[3];
    uint64_t pd4 = mbase[4], pd5 = mbase[5], pd6 = mbase[6], pd7 = mbase[7];
    uint64_t rwW = 0;
#define SCAN_STEP(K, PM, PD)                                          \
    {                                                                 \
      int i = i8 + K;                                                 \
      uint64_t m = PM, d = PD;                                        \
      int ii = i + 8;                                                 \
      if (ii < PRE) {                                                 \
        PM = mcol[ii];                                                \
        PD = mbase[(size_t)(ii >> 6) * PRE + ii];                     \
      }                                                               \
      if (!((rwW >> (i & 63)) & 1ull)) { remv |= m; rwW |= d; }       \
    }
    for (int i8 = 0; i8 < PRE; i8 += 8) {       // PRE = 125 * 8
      if ((i8 & 63) == 0) rwW = __shfl(remv, i8 >> 6, 64);  // refresh block word
      SCAN_STEP(0, pm0, pd0) SCAN_STEP(1, pm1, pd1)
      SCAN_STEP(2, pm2, pd2) SCAN_STEP(3, pm3, pd3)
      SCAN_STEP(4, pm4, pd4) SCAN_STEP(5, pm5, pd5)
      SCAN_STEP(6, pm6, pd6) SCAN_STEP(7, pm7, pd7)
    }
#undef SCAN_STEP
    if (lane < 16) kw[lane] = vw & ~remv;
  }
  __syncthreads();
  if (t == 0) {
    unsigned s = 0;
    for (int i = 0; i < 16; i++) { wp[i] = s; s += __popcll(kw[i]); }
    wp[16] = s;
  }
  __syncthreads();
  unsigned K = wp[16];
  float4* ob = (float4*)out;                      // boxes: [B][PRE][4]
  float* os = out + (size_t)BB * PRE * 4;         // scores: [B][PRE]
  for (int r = t; r < PRE; r += 256) {
    uint64_t wbits = kw[r >> 6];
    if ((wbits >> (r & 63)) & 1ull) {
      unsigned rank = wp[r >> 6] + (unsigned)__popcll(wbits & ((1ull << (r & 63)) - 1ull));
      ob[(size_t)b * PRE + rank] = bc[(size_t)b * PRE + r];
      os[(size_t)b * PRE + rank] = score[(size_t)b * PRE + r];
    }
  }
  for (int s2 = t; s2 < PRE; s2 += 256) {
    if (s2 >= (int)K) {
      ob[(size_t)b * PRE + s2] = make_float4(0.f, 0.f, 0.f, 0.f);
      os[(size_t)b * PRE + s2] = 0.0f;
    }
  }
}

extern "C" void kernel_launch(void* const* d_in, const int* in_sizes, int n_in,
                              void* d_out, int out_size, void* d_ws, size_t ws_size,
                              hipStream_t stream) {
  const float4* prop = (const float4*)d_in[0];
  const float*  obj  = (const float*)d_in[1];
  const int*    lvls = (const int*)d_in[2];
  const int*    ph   = (const int*)d_in[3];
  const int*    pw   = (const int*)d_in[4];
  unsigned char* ws = (unsigned char*)d_ws;

  uint16_t* hist16 = (uint16_t*)(ws);
  unsigned* cnt    = (unsigned*)(ws + OFF_CNT);
  unsigned* Tarr   = (unsigned*)(ws + OFF_T);
  float*    scale  = (float*)(ws + OFF_SCALE);
  uint64_t* cand   = (uint64_t*)(ws + OFF_CAND);
  float*    score  = (float*)(ws + OFF_SCORE);
  float4*   bc     = (float4*)(ws + OFF_BC);
  int*      lvlT   = (int*)(ws + OFF_LVL);
  uint64_t* validW = (uint64_t*)(ws + OFF_VALID);
  uint64_t* mask   = (uint64_t*)(ws + OFF_MASK);

  k_hist<<<dim3(HS, BB), 1024, 0, stream>>>((const float4*)obj, hist16);
  k_thresh<<<BB, 256, 0, stream>>>(hist16, Tarr, cnt);   // also zeroes cnt
  k_collect<<<dim3(CCHUNK, BB), 256, 0, stream>>>((const float4*)obj, Tarr, cnt, cand);
  k_sortprep<<<BB, 1024, 0, stream>>>(cand, cnt, prop, lvls, ph, pw,
                                      score, bc, lvlT, validW, scale);
  k_mask<<<dim3(16, BB), 256, 0, stream>>>(bc, lvlT, scale, mask);
  k_scanpack<<<BB, 256, 0, stream>>>(mask, validW, bc, score, (float*)d_out);
}